// Round 7
// baseline (267.925 us; speedup 1.0000x reference)
//
#include <hip/hip_runtime.h>
#include <math.h>

#define F 128
#define TWO_F 256
#define BN_EPS 1e-5f
#define PAD_W2 264   // bf16 row stride for W2T LDS (256+8)

typedef unsigned short ushort_t;
typedef unsigned char uchar_t;
typedef __attribute__((ext_vector_type(8))) short bfrag;   // 8 bf16
typedef __attribute__((ext_vector_type(4))) float ffrag;   // 4 fp32
typedef __attribute__((ext_vector_type(2))) float floatx2;

__device__ __forceinline__ float gelu_exact(float x) {
    return 0.5f * x * (1.0f + erff(x * 0.70710678118654752f));
}
__device__ __forceinline__ ushort_t f2bf(float x) {
    unsigned int u = __float_as_uint(x);
    u = (u + 0x7FFFu + ((u >> 16) & 1u)) >> 16;
    return (ushort_t)u;
}
__device__ __forceinline__ unsigned int pk2(float a, float b) {
    return (unsigned int)f2bf(a) | ((unsigned int)f2bf(b) << 16);
}

__device__ __forceinline__ void fma4_fp8(float* acc, unsigned int d, float w) {
    floatx2 lo = __builtin_amdgcn_cvt_pk_f32_fp8(d, false);
    floatx2 hi = __builtin_amdgcn_cvt_pk_f32_fp8(d, true);
    acc[0] = fmaf(w, lo.x, acc[0]);
    acc[1] = fmaf(w, lo.y, acc[1]);
    acc[2] = fmaf(w, hi.x, acc[2]);
    acc[3] = fmaf(w, hi.y, acc[3]);
}
__device__ __forceinline__ void fma16_fp8(float* acc, uint4 a, float w) {
    fma4_fp8(acc + 0,  a.x, w); fma4_fp8(acc + 4,  a.y, w);
    fma4_fp8(acc + 8,  a.z, w); fma4_fp8(acc + 12, a.w, w);
}

// pack 8 fp32 (two float4) -> one bfrag
__device__ __forceinline__ bfrag pack8(float4 f0, float4 f1) {
    bfrag a;
    unsigned int* au = reinterpret_cast<unsigned int*>(&a);
    au[0] = pk2(f0.x, f0.y); au[1] = pk2(f0.z, f0.w);
    au[2] = pk2(f1.x, f1.y); au[3] = pk2(f1.z, f1.w);
    return a;
}

// ---------------- fold (blocks 0..128) + hist (blocks 129+) in one dispatch ----------------
__global__ __launch_bounds__(256) void fold_hist(
    const float* __restrict__ pre_w, const float* __restrict__ pre_b,
    const float* __restrict__ g1, const float* __restrict__ be1,
    const float* __restrict__ m1, const float* __restrict__ v1,
    const float* __restrict__ upd_w, const float* __restrict__ upd_b,
    const float* __restrict__ g2, const float* __restrict__ be2,
    const float* __restrict__ m2, const float* __restrict__ v2,
    ushort_t* __restrict__ W1T, ushort_t* __restrict__ W2T,
    float* __restrict__ b1f, float* __restrict__ b2f,
    const int* __restrict__ edges, int* __restrict__ counts,
    int* __restrict__ rankb, int nEdges, int histBlocks) {
    const int t = threadIdx.x;
    if (blockIdx.x == 0) {
        __shared__ float t1[F], t2[TWO_F];
        if (t < F) {
            float s = g1[t] * rsqrtf(v1[t] + BN_EPS);
            t1[t] = be1[t] - m1[t] * s;
        }
        {
            float s = g2[t] * rsqrtf(v2[t] + BN_EPS);
            t2[t] = be2[t] - m2[t] * s;
        }
        __syncthreads();
        if (t < F) {
            float acc = pre_b[t];
            #pragma unroll 16
            for (int k = 0; k < F; ++k) acc = fmaf(t1[k], pre_w[k * F + t], acc);
            b1f[t] = acc;
        } else {
            int j = t - F;
            float acc = upd_b[j];
            #pragma unroll 16
            for (int k = 0; k < TWO_F; ++k) acc = fmaf(t2[k], upd_w[k * F + j], acc);
            b2f[j] = acc;
        }
    } else if (blockIdx.x <= 128) {
        int idx = (blockIdx.x - 1) * 256 + t;
        if (idx < F * F) {
            int k = idx & (F - 1), n = idx >> 7;
            float s = g1[k] * rsqrtf(v1[k] + BN_EPS);
            W1T[idx] = f2bf(s * pre_w[k * F + n]);
        }
        {
            int k = idx & (TWO_F - 1), n = idx >> 8;
            float s = g2[k] * rsqrtf(v2[k] + BN_EPS);
            W2T[idx] = f2bf(s * upd_w[k * F + n]);
        }
    } else {
        int b = blockIdx.x - 129;
        for (int i = b * 256 + t; i < nEdges; i += histBlocks * 256) {
            int rk = atomicAdd(&counts[edges[i]], 1);
            rankb[i] = rk;
        }
    }
}

// ---------------- CSR scans ----------------
__global__ __launch_bounds__(1024) void scan_pass1(const int* __restrict__ counts,
                                                   int* __restrict__ offsets,
                                                   int* __restrict__ blocksums, int n) {
    __shared__ int sb[1024];
    const int t = threadIdx.x;
    int idx = blockIdx.x * 1024 + t;
    int v = (idx < n) ? counts[idx] : 0;
    sb[t] = v;
    __syncthreads();
    for (int off = 1; off < 1024; off <<= 1) {
        int x = (t >= off) ? sb[t - off] : 0;
        __syncthreads();
        sb[t] += x;
        __syncthreads();
    }
    if (idx < n) offsets[idx + 1] = sb[t];
    if (t == 1023) blocksums[blockIdx.x] = sb[t];
}

__global__ __launch_bounds__(1024) void scan_pass3(const int* __restrict__ counts,
                                                   int* __restrict__ offsets,
                                                   const int* __restrict__ blocksums,
                                                   int* __restrict__ cursor, int n) {
    __shared__ int sb[1024];
    const int t = threadIdx.x;
    sb[t] = (t < blockIdx.x) ? blocksums[t] : 0;
    __syncthreads();
    #pragma unroll
    for (int off = 512; off > 0; off >>= 1) {
        if (t < off) sb[t] += sb[t + off];
        __syncthreads();
    }
    int base = sb[0];
    int idx = blockIdx.x * 1024 + t;
    if (idx < n) {
        int incl = offsets[idx + 1] + base;
        offsets[idx + 1] = incl;
        cursor[idx] = incl - counts[idx];
    }
    if (blockIdx.x == 0 && t == 0) offsets[0] = 0;
}

// ---------------- gemm1 (zero-LDS, W in registers, operand-swapped, 256-node tiles) + fill ----------------
// 4 waves x 32-feature slice; per-wave W-slice = 8 bfrags in VGPRs, loaded ONCE per block
// and amortized over 16 node-groups (256 nodes). D[feat][node] -> 4 consecutive feats/lane
// -> 2x cvt_pk_fp8 -> direct dword store to G8. No LDS, no barriers.
__global__ __launch_bounds__(256) void gemm1_fill(
    const float* __restrict__ nodes, const ushort_t* __restrict__ W1T,
    const float* __restrict__ b1f, uchar_t* __restrict__ G8, int nNodes,
    const int* __restrict__ edges, const float* __restrict__ ew,
    const int* __restrict__ offsets, const int* __restrict__ rankb,
    int2* __restrict__ csr, int nEdges, int gemmBlocks, int fillBlocks) {
    const int t = threadIdx.x;

    if (blockIdx.x >= gemmBlocks) {   // fill part: no atomics, pure scatter
        int b = blockIdx.x - gemmBlocks;
        for (int e = b * 256 + t; e < nEdges; e += fillBlocks * 256) {
            int dst = edges[e];
            int pos = offsets[dst] + rankb[e];
            csr[pos] = make_int2(edges[nEdges + e], __float_as_int(ew[e]));
        }
        return;
    }

    const int lane = t & 63, w = t >> 6;
    const int m = lane & 15, quad = lane >> 4;
    const int fw = w * 32;   // wave's 32-feature slice

    // W-slice frags in registers (A-operand after swap): feat row = m, k = quad*8..
    bfrag wf[2][4];
    #pragma unroll
    for (int cb = 0; cb < 2; ++cb)
        #pragma unroll
        for (int kk = 0; kk < 4; ++kk)
            wf[cb][kk] = *reinterpret_cast<const bfrag*>(
                W1T + (size_t)(fw + cb * 16 + m) * F + kk * 32 + quad * 8);

    float4 bias[2];
    #pragma unroll
    for (int cb = 0; cb < 2; ++cb)
        bias[cb] = *reinterpret_cast<const float4*>(b1f + fw + cb * 16 + quad * 4);

    const int tb = blockIdx.x * 256;   // 256-node tile per block

    #pragma unroll 2
    for (int g = 0; g < 16; ++g) {
        const int node = tb + g * 16 + m;
        const int sn = (node < nNodes) ? node : 0;
        const float* np = nodes + (size_t)sn * F + quad * 8;

        bfrag nf[4];
        #pragma unroll
        for (int kk = 0; kk < 4; ++kk) {
            float4 f0 = *reinterpret_cast<const float4*>(np + kk * 32);
            float4 f1 = *reinterpret_cast<const float4*>(np + kk * 32 + 4);
            nf[kk] = pack8(f0, f1);
        }

        ffrag acc[2];
        acc[0] = (ffrag){0.f, 0.f, 0.f, 0.f};
        acc[1] = (ffrag){0.f, 0.f, 0.f, 0.f};
        #pragma unroll
        for (int kk = 0; kk < 4; ++kk) {
            acc[0] = __builtin_amdgcn_mfma_f32_16x16x32_bf16(wf[0][kk], nf[kk], acc[0], 0, 0, 0);
            acc[1] = __builtin_amdgcn_mfma_f32_16x16x32_bf16(wf[1][kk], nf[kk], acc[1], 0, 0, 0);
        }

        if (node < nNodes) {
            #pragma unroll
            for (int cb = 0; cb < 2; ++cb) {
                float v0 = gelu_exact(acc[cb][0] + bias[cb].x);
                float v1 = gelu_exact(acc[cb][1] + bias[cb].y);
                float v2 = gelu_exact(acc[cb][2] + bias[cb].z);
                float v3 = gelu_exact(acc[cb][3] + bias[cb].w);
                int pw = __builtin_amdgcn_cvt_pk_fp8_f32(v0, v1, 0, false);
                pw = __builtin_amdgcn_cvt_pk_fp8_f32(v2, v3, pw, true);
                *reinterpret_cast<unsigned int*>(
                    G8 + (size_t)node * F + fw + cb * 16 + quad * 4) = (unsigned int)pw;
            }
        }
    }
}

// ---------------- gather_agg: pure aggregation, no LDS, no barriers ----------------
__global__ __launch_bounds__(256) void gather_agg(
    const uchar_t* __restrict__ G8, const int* __restrict__ offsets,
    const int2* __restrict__ csr, ushort_t* __restrict__ agg, int nNodes) {
    const int t = threadIdx.x;
    const int gid = blockIdx.x * 32 + (t >> 3);
    const int q = t & 7;
    if (gid >= nNodes) return;
    const int s = offsets[gid], e = offsets[gid + 1];

    float acc[16];
    #pragma unroll
    for (int j = 0; j < 16; ++j) acc[j] = 0.f;

    int i = s;
    while (i < e) {
        int c = e - i;
        c = (c > 8) ? 8 : c;
        uint4 av[8];
        float wv[8];
        #pragma unroll
        for (int j = 0; j < 8; ++j) {
            if (j < c) {
                int2 m = csr[i + j];
                wv[j] = __int_as_float(m.y);
                av[j] = *reinterpret_cast<const uint4*>(
                    G8 + (size_t)(unsigned int)m.x * F + q * 16);
            }
        }
        #pragma unroll
        for (int j = 0; j < 8; ++j)
            if (j < c) fma16_fp8(acc, av[j], wv[j]);
        i += c;
    }

    const int deg = e - s;
    const float inv = (deg > 0) ? 1.0f / ((float)deg * (float)F) : 0.f;  // counter = deg*F quirk
    uint4 pv0, pv1;
    pv0.x = pk2(acc[0] * inv, acc[1] * inv);  pv0.y = pk2(acc[2] * inv, acc[3] * inv);
    pv0.z = pk2(acc[4] * inv, acc[5] * inv);  pv0.w = pk2(acc[6] * inv, acc[7] * inv);
    pv1.x = pk2(acc[8] * inv, acc[9] * inv);  pv1.y = pk2(acc[10] * inv, acc[11] * inv);
    pv1.z = pk2(acc[12] * inv, acc[13] * inv); pv1.w = pk2(acc[14] * inv, acc[15] * inv);
    uint4* d = reinterpret_cast<uint4*>(agg + (size_t)gid * F + q * 16);
    d[0] = pv0; d[1] = pv1;
}

// ---------------- gemm2: [nodes fp32 (packed in-reg) | agg bf16] x W2T -> gelu -> out ----------------
// 512 threads = 8 waves; each wave 32 rows (2 row-frags, B reuse x2); block tile = 256 rows.
__global__ __launch_bounds__(512, 4) void gemm2(
    const float* __restrict__ nodes, const ushort_t* __restrict__ agg,
    const ushort_t* __restrict__ W2T, const float* __restrict__ b2f,
    float* __restrict__ out, int nNodes) {
    __shared__ ushort_t Wl[F * PAD_W2];   // 67.6 KB
    __shared__ float bsm[F];
    const int t = threadIdx.x;

    for (int j = t; j < 4096; j += 512) {
        int feat = j >> 5, kc = j & 31;
        *reinterpret_cast<uint4*>(Wl + feat * PAD_W2 + kc * 8) =
            reinterpret_cast<const uint4*>(W2T)[j];
    }
    if (t < F) bsm[t] = b2f[t];
    __syncthreads();

    const int lane = t & 63, w = t >> 6;
    const int m = lane & 15, quad = lane >> 4;
    const int tb = blockIdx.x * 256;

    int row0 = tb + w * 32 + m;
    int row1 = row0 + 16;
    int r0c = (row0 < nNodes) ? row0 : 0;
    int r1c = (row1 < nNodes) ? row1 : 0;
    const float*    p0n = nodes + (size_t)r0c * F + quad * 8;
    const float*    p1n = nodes + (size_t)r1c * F + quad * 8;
    const ushort_t* p0a = agg   + (size_t)r0c * F + quad * 8;
    const ushort_t* p1a = agg   + (size_t)r1c * F + quad * 8;

    ffrag acc0[8], acc1[8];
    #pragma unroll
    for (int c = 0; c < 8; ++c) {
        acc0[c] = (ffrag){0.f, 0.f, 0.f, 0.f};
        acc1[c] = (ffrag){0.f, 0.f, 0.f, 0.f};
    }

    #pragma unroll
    for (int kk = 0; kk < 8; ++kk) {
        int k0 = kk * 32 + quad * 8;
        bfrag a0, a1;
        if (kk < 4) {
            float4 f0 = *reinterpret_cast<const float4*>(p0n + kk * 32);
            float4 f1 = *reinterpret_cast<const float4*>(p0n + kk * 32 + 4);
            a0 = pack8(f0, f1);
            float4 g0 = *reinterpret_cast<const float4*>(p1n + kk * 32);
            float4 g1 = *reinterpret_cast<const float4*>(p1n + kk * 32 + 4);
            a1 = pack8(g0, g1);
        } else {
            a0 = *reinterpret_cast<const bfrag*>(p0a + (kk - 4) * 32);
            a1 = *reinterpret_cast<const bfrag*>(p1a + (kk - 4) * 32);
        }
        #pragma unroll
        for (int c = 0; c < 8; ++c) {
            bfrag b = *reinterpret_cast<const bfrag*>(Wl + (c * 16 + m) * PAD_W2 + k0);
            acc0[c] = __builtin_amdgcn_mfma_f32_16x16x32_bf16(a0, b, acc0[c], 0, 0, 0);
            acc1[c] = __builtin_amdgcn_mfma_f32_16x16x32_bf16(a1, b, acc1[c], 0, 0, 0);
        }
    }

    #pragma unroll
    for (int c = 0; c < 8; ++c) {
        int feat = c * 16 + m;
        float bj = bsm[feat];
        #pragma unroll
        for (int i = 0; i < 4; ++i) {
            int n0 = tb + w * 32 + quad * 4 + i;
            if (n0 < nNodes) out[(size_t)n0 * F + feat] = gelu_exact(acc0[c][i] + bj);
            int n1 = n0 + 16;
            if (n1 < nNodes) out[(size_t)n1 * F + feat] = gelu_exact(acc1[c][i] + bj);
        }
    }
}

extern "C" void kernel_launch(void* const* d_in, const int* in_sizes, int n_in,
                              void* d_out, int out_size, void* d_ws, size_t ws_size,
                              hipStream_t stream) {
    const float* nodes  = (const float*)d_in[0];
    const int*   edges  = (const int*)d_in[1];
    const float* ew     = (const float*)d_in[2];
    const float* pre_g  = (const float*)d_in[3];
    const float* pre_be = (const float*)d_in[4];
    const float* pre_m  = (const float*)d_in[5];
    const float* pre_v  = (const float*)d_in[6];
    const float* pre_w  = (const float*)d_in[7];
    const float* pre_b  = (const float*)d_in[8];
    const float* upd_g  = (const float*)d_in[9];
    const float* upd_be = (const float*)d_in[10];
    const float* upd_m  = (const float*)d_in[11];
    const float* upd_v  = (const float*)d_in[12];
    const float* upd_w  = (const float*)d_in[13];
    const float* upd_b  = (const float*)d_in[14];
    float* out = (float*)d_out;

    const int nNodes = in_sizes[0] / F;
    const int nEdges = in_sizes[2];
    const int nChunks = (nNodes + 1023) / 1024;
    const int histBlocks = 1024;
    const int fillBlocks = 512;
    const int gemmBlocks = (nNodes + 255) / 256;   // 256-node tiles

    // ws layout (16B aligned blocks)
    char* p = (char*)d_ws;
    int*      counts    = (int*)p;       p += (size_t)nNodes * 4;
    int*      offsets   = (int*)p;       p += (size_t)(nNodes + 4) * 4;
    int*      cursor    = (int*)p;       p += (size_t)nNodes * 4;
    int*      blocksums = (int*)p;       p += 1024 * 4;
    int2*     csr       = (int2*)p;      p += (size_t)nEdges * 8;
    float*    b1f       = (float*)p;     p += F * 4;
    float*    b2f       = (float*)p;     p += F * 4;
    ushort_t* W1T       = (ushort_t*)p;  p += F * F * 2;
    ushort_t* W2T       = (ushort_t*)p;  p += TWO_F * F * 2;
    uchar_t*  G8        = (uchar_t*)p;   p += (size_t)nNodes * F;
    ushort_t* agg       = (ushort_t*)p;  p += (size_t)nNodes * F * 2;
    int*      rankb     = (int*)p;       // nEdges * 4

    hipMemsetAsync(counts, 0, (size_t)nNodes * 4, stream);

    fold_hist<<<129 + histBlocks, 256, 0, stream>>>(
        pre_w, pre_b, pre_g, pre_be, pre_m, pre_v,
        upd_w, upd_b, upd_g, upd_be, upd_m, upd_v,
        W1T, W2T, b1f, b2f, edges, counts, rankb, nEdges, histBlocks);

    scan_pass1<<<nChunks, 1024, 0, stream>>>(counts, offsets, blocksums, nNodes);
    scan_pass3<<<nChunks, 1024, 0, stream>>>(counts, offsets, blocksums, cursor, nNodes);

    gemm1_fill<<<gemmBlocks + fillBlocks, 256, 0, stream>>>(
        nodes, W1T, b1f, G8, nNodes, edges, ew, offsets, rankb, csr, nEdges,
        gemmBlocks, fillBlocks);

    gather_agg<<<(nNodes + 31) / 32, 256, 0, stream>>>(
        G8, offsets, csr, agg, nNodes);

    gemm2<<<(nNodes + 255) / 256, 512, 0, stream>>>(
        nodes, agg, W2T, b2f, out, nNodes);
}

// Round 8
// 250.344 us; speedup vs baseline: 1.0702x; 1.0702x over previous
//
#include <hip/hip_runtime.h>
#include <math.h>

#define F 128
#define TWO_F 256
#define BN_EPS 1e-5f
#define PAD_W1 136   // bf16 row stride for W1T LDS (128+8)
#define PAD_W2 264   // bf16 row stride for W2T LDS (256+8)

typedef unsigned short ushort_t;
typedef unsigned char uchar_t;
typedef __attribute__((ext_vector_type(8))) short bfrag;   // 8 bf16
typedef __attribute__((ext_vector_type(4))) float ffrag;   // 4 fp32
typedef __attribute__((ext_vector_type(2))) float floatx2;

__device__ __forceinline__ float gelu_exact(float x) {
    return 0.5f * x * (1.0f + erff(x * 0.70710678118654752f));
}
__device__ __forceinline__ ushort_t f2bf(float x) {
    unsigned int u = __float_as_uint(x);
    u = (u + 0x7FFFu + ((u >> 16) & 1u)) >> 16;
    return (ushort_t)u;
}
__device__ __forceinline__ unsigned int pk2(float a, float b) {
    return (unsigned int)f2bf(a) | ((unsigned int)f2bf(b) << 16);
}

__device__ __forceinline__ void fma4_fp8(float* acc, unsigned int d, float w) {
    floatx2 lo = __builtin_amdgcn_cvt_pk_f32_fp8(d, false);
    floatx2 hi = __builtin_amdgcn_cvt_pk_f32_fp8(d, true);
    acc[0] = fmaf(w, lo.x, acc[0]);
    acc[1] = fmaf(w, lo.y, acc[1]);
    acc[2] = fmaf(w, hi.x, acc[2]);
    acc[3] = fmaf(w, hi.y, acc[3]);
}
__device__ __forceinline__ void fma16_fp8(float* acc, uint4 a, float w) {
    fma4_fp8(acc + 0,  a.x, w); fma4_fp8(acc + 4,  a.y, w);
    fma4_fp8(acc + 8,  a.z, w); fma4_fp8(acc + 12, a.w, w);
}

// pack 8 fp32 (two float4) -> one bfrag
__device__ __forceinline__ bfrag pack8(float4 f0, float4 f1) {
    bfrag a;
    unsigned int* au = reinterpret_cast<unsigned int*>(&a);
    au[0] = pk2(f0.x, f0.y); au[1] = pk2(f0.z, f0.w);
    au[2] = pk2(f1.x, f1.y); au[3] = pk2(f1.z, f1.w);
    return a;
}

// ---------------- fold (blocks 0..128) + hist (blocks 129+) in one dispatch ----------------
__global__ __launch_bounds__(256) void fold_hist(
    const float* __restrict__ pre_w, const float* __restrict__ pre_b,
    const float* __restrict__ g1, const float* __restrict__ be1,
    const float* __restrict__ m1, const float* __restrict__ v1,
    const float* __restrict__ upd_w, const float* __restrict__ upd_b,
    const float* __restrict__ g2, const float* __restrict__ be2,
    const float* __restrict__ m2, const float* __restrict__ v2,
    ushort_t* __restrict__ W1T, ushort_t* __restrict__ W2T,
    float* __restrict__ b1f, float* __restrict__ b2f,
    const int* __restrict__ edges, int* __restrict__ counts,
    int* __restrict__ rankb, int nEdges, int histBlocks) {
    const int t = threadIdx.x;
    if (blockIdx.x == 0) {
        __shared__ float t1[F], t2[TWO_F];
        if (t < F) {
            float s = g1[t] * rsqrtf(v1[t] + BN_EPS);
            t1[t] = be1[t] - m1[t] * s;
        }
        {
            float s = g2[t] * rsqrtf(v2[t] + BN_EPS);
            t2[t] = be2[t] - m2[t] * s;
        }
        __syncthreads();
        if (t < F) {
            float acc = pre_b[t];
            #pragma unroll 16
            for (int k = 0; k < F; ++k) acc = fmaf(t1[k], pre_w[k * F + t], acc);
            b1f[t] = acc;
        } else {
            int j = t - F;
            float acc = upd_b[j];
            #pragma unroll 16
            for (int k = 0; k < TWO_F; ++k) acc = fmaf(t2[k], upd_w[k * F + j], acc);
            b2f[j] = acc;
        }
    } else if (blockIdx.x <= 128) {
        int idx = (blockIdx.x - 1) * 256 + t;
        if (idx < F * F) {
            int k = idx & (F - 1), n = idx >> 7;
            float s = g1[k] * rsqrtf(v1[k] + BN_EPS);
            W1T[idx] = f2bf(s * pre_w[k * F + n]);
        }
        {
            int k = idx & (TWO_F - 1), n = idx >> 8;
            float s = g2[k] * rsqrtf(v2[k] + BN_EPS);
            W2T[idx] = f2bf(s * upd_w[k * F + n]);
        }
    } else {
        int b = blockIdx.x - 129;
        for (int i = b * 256 + t; i < nEdges; i += histBlocks * 256) {
            int rk = atomicAdd(&counts[edges[i]], 1);
            rankb[i] = rk;
        }
    }
}

// ---------------- CSR scans ----------------
__global__ __launch_bounds__(1024) void scan_pass1(const int* __restrict__ counts,
                                                   int* __restrict__ offsets,
                                                   int* __restrict__ blocksums, int n) {
    __shared__ int sb[1024];
    const int t = threadIdx.x;
    int idx = blockIdx.x * 1024 + t;
    int v = (idx < n) ? counts[idx] : 0;
    sb[t] = v;
    __syncthreads();
    for (int off = 1; off < 1024; off <<= 1) {
        int x = (t >= off) ? sb[t - off] : 0;
        __syncthreads();
        sb[t] += x;
        __syncthreads();
    }
    if (idx < n) offsets[idx + 1] = sb[t];
    if (t == 1023) blocksums[blockIdx.x] = sb[t];
}

__global__ __launch_bounds__(1024) void scan_pass3(const int* __restrict__ counts,
                                                   int* __restrict__ offsets,
                                                   const int* __restrict__ blocksums,
                                                   int* __restrict__ cursor, int n) {
    __shared__ int sb[1024];
    const int t = threadIdx.x;
    sb[t] = (t < blockIdx.x) ? blocksums[t] : 0;
    __syncthreads();
    #pragma unroll
    for (int off = 512; off > 0; off >>= 1) {
        if (t < off) sb[t] += sb[t + off];
        __syncthreads();
    }
    int base = sb[0];
    int idx = blockIdx.x * 1024 + t;
    if (idx < n) {
        int incl = offsets[idx + 1] + base;
        offsets[idx + 1] = incl;
        cursor[idx] = incl - counts[idx];
    }
    if (blockIdx.x == 0 && t == 0) offsets[0] = 0;
}

// ---------------- gemm1 (swapped operands, W1T in LDS, persistent 4 blocks/CU) + fill ----------------
// A = W1T slice from LDS (ds_read_b128, 2-way conflicts only), B = 16 node rows packed
// in-register. Each wave owns 16 nodes/tile (no redundant node reads). D[feat][node]:
// lane holds 4 consecutive feats of one node -> 2x cvt_pk_fp8 -> direct dword G8 store.
__global__ __launch_bounds__(256) void gemm1_fill(
    const float* __restrict__ nodes, const ushort_t* __restrict__ W1T,
    const float* __restrict__ b1f, uchar_t* __restrict__ G8, int nNodes,
    const int* __restrict__ edges, const float* __restrict__ ew,
    const int* __restrict__ offsets, const int* __restrict__ rankb,
    int2* __restrict__ csr, int nEdges, int gemmBlocks, int fillBlocks, int nTiles) {
    __shared__ ushort_t Wl[F * PAD_W1];    // 34.8 KB -> 4 blocks/CU
    __shared__ float bsm[F];
    const int t = threadIdx.x;

    if (blockIdx.x >= gemmBlocks) {   // fill part: no atomics, pure scatter
        int b = blockIdx.x - gemmBlocks;
        for (int e = b * 256 + t; e < nEdges; e += fillBlocks * 256) {
            int dst = edges[e];
            int pos = offsets[dst] + rankb[e];
            csr[pos] = make_int2(edges[nEdges + e], __float_as_int(ew[e]));
        }
        return;
    }

    // stage W1T -> LDS (padded), once per persistent block
    for (int j = t; j < 2048; j += 256) {
        int feat = j >> 4, kc = j & 15;
        *reinterpret_cast<uint4*>(Wl + feat * PAD_W1 + kc * 8) =
            reinterpret_cast<const uint4*>(W1T)[j];
    }
    if (t < F) bsm[t] = b1f[t];
    __syncthreads();

    const int lane = t & 63, w = t >> 6;
    const int m = lane & 15, quad = lane >> 4;

    for (int tile = blockIdx.x; tile < nTiles; tile += gemmBlocks) {
        const int node = tile * 64 + w * 16 + m;
        const int sn = (node < nNodes) ? node : 0;
        const float* np = nodes + (size_t)sn * F + quad * 8;

        bfrag nf[4];
        #pragma unroll
        for (int kk = 0; kk < 4; ++kk) {
            float4 f0 = *reinterpret_cast<const float4*>(np + kk * 32);
            float4 f1 = *reinterpret_cast<const float4*>(np + kk * 32 + 4);
            nf[kk] = pack8(f0, f1);
        }

        ffrag acc[8];
        #pragma unroll
        for (int cb = 0; cb < 8; ++cb) acc[cb] = (ffrag){0.f, 0.f, 0.f, 0.f};

        #pragma unroll
        for (int kk = 0; kk < 4; ++kk) {
            int ko = kk * 32 + quad * 8;
            #pragma unroll
            for (int cb = 0; cb < 8; ++cb) {
                bfrag a = *reinterpret_cast<const bfrag*>(Wl + (cb * 16 + m) * PAD_W1 + ko);
                acc[cb] = __builtin_amdgcn_mfma_f32_16x16x32_bf16(a, nf[kk], acc[cb], 0, 0, 0);
            }
        }

        if (node < nNodes) {
            #pragma unroll
            for (int cb = 0; cb < 8; ++cb) {
                float4 bj = *reinterpret_cast<const float4*>(bsm + cb * 16 + quad * 4);
                float v0 = gelu_exact(acc[cb][0] + bj.x);
                float v1 = gelu_exact(acc[cb][1] + bj.y);
                float v2 = gelu_exact(acc[cb][2] + bj.z);
                float v3 = gelu_exact(acc[cb][3] + bj.w);
                int pw = __builtin_amdgcn_cvt_pk_fp8_f32(v0, v1, 0, false);
                pw = __builtin_amdgcn_cvt_pk_fp8_f32(v2, v3, pw, true);
                *reinterpret_cast<unsigned int*>(
                    G8 + (size_t)node * F + cb * 16 + quad * 4) = (unsigned int)pw;
            }
        }
    }
}

// ---------------- gather_agg: pure aggregation, no LDS, no barriers ----------------
__global__ __launch_bounds__(256) void gather_agg(
    const uchar_t* __restrict__ G8, const int* __restrict__ offsets,
    const int2* __restrict__ csr, ushort_t* __restrict__ agg, int nNodes) {
    const int t = threadIdx.x;
    const int gid = blockIdx.x * 32 + (t >> 3);
    const int q = t & 7;
    if (gid >= nNodes) return;
    const int s = offsets[gid], e = offsets[gid + 1];

    float acc[16];
    #pragma unroll
    for (int j = 0; j < 16; ++j) acc[j] = 0.f;

    int i = s;
    while (i < e) {
        int c = e - i;
        c = (c > 8) ? 8 : c;
        uint4 av[8];
        float wv[8];
        #pragma unroll
        for (int j = 0; j < 8; ++j) {
            if (j < c) {
                int2 m = csr[i + j];
                wv[j] = __int_as_float(m.y);
                av[j] = *reinterpret_cast<const uint4*>(
                    G8 + (size_t)(unsigned int)m.x * F + q * 16);
            }
        }
        #pragma unroll
        for (int j = 0; j < 8; ++j)
            if (j < c) fma16_fp8(acc, av[j], wv[j]);
        i += c;
    }

    const int deg = e - s;
    const float inv = (deg > 0) ? 1.0f / ((float)deg * (float)F) : 0.f;  // counter = deg*F quirk
    uint4 pv0, pv1;
    pv0.x = pk2(acc[0] * inv, acc[1] * inv);  pv0.y = pk2(acc[2] * inv, acc[3] * inv);
    pv0.z = pk2(acc[4] * inv, acc[5] * inv);  pv0.w = pk2(acc[6] * inv, acc[7] * inv);
    pv1.x = pk2(acc[8] * inv, acc[9] * inv);  pv1.y = pk2(acc[10] * inv, acc[11] * inv);
    pv1.z = pk2(acc[12] * inv, acc[13] * inv); pv1.w = pk2(acc[14] * inv, acc[15] * inv);
    uint4* d = reinterpret_cast<uint4*>(agg + (size_t)gid * F + q * 16);
    d[0] = pv0; d[1] = pv1;
}

// ---------------- gemm2 (swapped operands, W2T in LDS, 512 thr, 128-node tiles) ----------------
// A = W2T from LDS, B = [nodes fp32 packed | agg bf16] per-lane node rows. 8 waves x 16
// nodes = 128-node tile; 2 blocks/CU (67.6 KB) -> 16 waves/CU. D[feat][node]: lane holds
// 4 consecutive feats of one node -> float4 out stores (64B-contiguous per node).
__global__ __launch_bounds__(512) void gemm2(
    const float* __restrict__ nodes, const ushort_t* __restrict__ agg,
    const ushort_t* __restrict__ W2T, const float* __restrict__ b2f,
    float* __restrict__ out, int nNodes) {
    __shared__ ushort_t Wl[F * PAD_W2];   // 67.6 KB
    __shared__ float bsm[F];
    const int t = threadIdx.x;

    for (int j = t; j < 4096; j += 512) {
        int feat = j >> 5, kc = j & 31;
        *reinterpret_cast<uint4*>(Wl + feat * PAD_W2 + kc * 8) =
            reinterpret_cast<const uint4*>(W2T)[j];
    }
    if (t < F) bsm[t] = b2f[t];
    __syncthreads();

    const int lane = t & 63, w = t >> 6;
    const int m = lane & 15, quad = lane >> 4;

    const int node = blockIdx.x * 128 + w * 16 + m;
    const int sn = (node < nNodes) ? node : 0;
    const float*    np = nodes + (size_t)sn * F + quad * 8;
    const ushort_t* pa = agg   + (size_t)sn * F + quad * 8;

    bfrag nf[8];
    #pragma unroll
    for (int kk = 0; kk < 4; ++kk) {
        float4 f0 = *reinterpret_cast<const float4*>(np + kk * 32);
        float4 f1 = *reinterpret_cast<const float4*>(np + kk * 32 + 4);
        nf[kk] = pack8(f0, f1);
    }
    #pragma unroll
    for (int kk = 4; kk < 8; ++kk)
        nf[kk] = *reinterpret_cast<const bfrag*>(pa + (kk - 4) * 32);

    ffrag acc[8];
    #pragma unroll
    for (int cb = 0; cb < 8; ++cb) acc[cb] = (ffrag){0.f, 0.f, 0.f, 0.f};

    #pragma unroll
    for (int kk = 0; kk < 8; ++kk) {
        int ko = kk * 32 + quad * 8;
        #pragma unroll
        for (int cb = 0; cb < 8; ++cb) {
            bfrag a = *reinterpret_cast<const bfrag*>(Wl + (cb * 16 + m) * PAD_W2 + ko);
            acc[cb] = __builtin_amdgcn_mfma_f32_16x16x32_bf16(a, nf[kk], acc[cb], 0, 0, 0);
        }
    }

    if (node < nNodes) {
        #pragma unroll
        for (int cb = 0; cb < 8; ++cb) {
            float4 bj = *reinterpret_cast<const float4*>(bsm + cb * 16 + quad * 4);
            float4 o;
            o.x = gelu_exact(acc[cb][0] + bj.x);
            o.y = gelu_exact(acc[cb][1] + bj.y);
            o.z = gelu_exact(acc[cb][2] + bj.z);
            o.w = gelu_exact(acc[cb][3] + bj.w);
            *reinterpret_cast<float4*>(out + (size_t)node * F + cb * 16 + quad * 4) = o;
        }
    }
}

extern "C" void kernel_launch(void* const* d_in, const int* in_sizes, int n_in,
                              void* d_out, int out_size, void* d_ws, size_t ws_size,
                              hipStream_t stream) {
    const float* nodes  = (const float*)d_in[0];
    const int*   edges  = (const int*)d_in[1];
    const float* ew     = (const float*)d_in[2];
    const float* pre_g  = (const float*)d_in[3];
    const float* pre_be = (const float*)d_in[4];
    const float* pre_m  = (const float*)d_in[5];
    const float* pre_v  = (const float*)d_in[6];
    const float* pre_w  = (const float*)d_in[7];
    const float* pre_b  = (const float*)d_in[8];
    const float* upd_g  = (const float*)d_in[9];
    const float* upd_be = (const float*)d_in[10];
    const float* upd_m  = (const float*)d_in[11];
    const float* upd_v  = (const float*)d_in[12];
    const float* upd_w  = (const float*)d_in[13];
    const float* upd_b  = (const float*)d_in[14];
    float* out = (float*)d_out;

    const int nNodes = in_sizes[0] / F;
    const int nEdges = in_sizes[2];
    const int nChunks = (nNodes + 1023) / 1024;
    const int histBlocks = 1024;
    const int fillBlocks = 512;
    const int nTiles = (nNodes + 63) / 64;
    const int gemmBlocks = (nTiles < 1024) ? nTiles : 1024;   // 4 blocks/CU persistent

    // ws layout (16B aligned blocks)
    char* p = (char*)d_ws;
    int*      counts    = (int*)p;       p += (size_t)nNodes * 4;
    int*      offsets   = (int*)p;       p += (size_t)(nNodes + 4) * 4;
    int*      cursor    = (int*)p;       p += (size_t)nNodes * 4;
    int*      blocksums = (int*)p;       p += 1024 * 4;
    int2*     csr       = (int2*)p;      p += (size_t)nEdges * 8;
    float*    b1f       = (float*)p;     p += F * 4;
    float*    b2f       = (float*)p;     p += F * 4;
    ushort_t* W1T       = (ushort_t*)p;  p += F * F * 2;
    ushort_t* W2T       = (ushort_t*)p;  p += TWO_F * F * 2;
    uchar_t*  G8        = (uchar_t*)p;   p += (size_t)nNodes * F;
    ushort_t* agg       = (ushort_t*)p;  p += (size_t)nNodes * F * 2;
    int*      rankb     = (int*)p;       // nEdges * 4

    hipMemsetAsync(counts, 0, (size_t)nNodes * 4, stream);

    fold_hist<<<129 + histBlocks, 256, 0, stream>>>(
        pre_w, pre_b, pre_g, pre_be, pre_m, pre_v,
        upd_w, upd_b, upd_g, upd_be, upd_m, upd_v,
        W1T, W2T, b1f, b2f, edges, counts, rankb, nEdges, histBlocks);

    scan_pass1<<<nChunks, 1024, 0, stream>>>(counts, offsets, blocksums, nNodes);
    scan_pass3<<<nChunks, 1024, 0, stream>>>(counts, offsets, blocksums, cursor, nNodes);

    gemm1_fill<<<gemmBlocks + fillBlocks, 256, 0, stream>>>(
        nodes, W1T, b1f, G8, nNodes, edges, ew, offsets, rankb, csr, nEdges,
        gemmBlocks, fillBlocks, nTiles);

    gather_agg<<<(nNodes + 31) / 32, 256, 0, stream>>>(
        G8, offsets, csr, agg, nNodes);

    gemm2<<<(nNodes + 127) / 128, 512, 0, stream>>>(
        nodes, agg, W2T, b2f, out, nNodes);
}

// Round 10
// 245.243 us; speedup vs baseline: 1.0925x; 1.0208x over previous
//
#include <hip/hip_runtime.h>
#include <math.h>

#define F 128
#define TWO_F 256
#define BN_EPS 1e-5f

typedef unsigned short ushort_t;
typedef unsigned char uchar_t;
typedef __attribute__((ext_vector_type(8))) short bfrag;   // 8 bf16
typedef __attribute__((ext_vector_type(4))) float ffrag;   // 4 fp32
typedef __attribute__((ext_vector_type(2))) float floatx2;

// exact-tolerance gelu: erf via Abramowitz-Stegun 7.1.26 (|err| < 1.5e-7)
__device__ __forceinline__ float gelu_exact(float x) {
    float a = fabsf(x) * 0.70710678118654752f;
    float t = __fdividef(1.0f, fmaf(0.3275911f, a, 1.0f));
    float poly = fmaf(fmaf(fmaf(fmaf(1.061405429f, t, -1.453152027f),
                               t, 1.421413741f), t, -0.284496736f), t, 0.254829592f) * t;
    float e = __expf(-a * a);
    float erf_a = fmaf(-poly, e, 1.0f);
    float erf_y = copysignf(erf_a, x);
    return 0.5f * x * (1.0f + erf_y);
}
__device__ __forceinline__ ushort_t f2bf(float x) {
    unsigned int u = __float_as_uint(x);
    u = (u + 0x7FFFu + ((u >> 16) & 1u)) >> 16;
    return (ushort_t)u;
}
__device__ __forceinline__ unsigned int pk2(float a, float b) {
    return (unsigned int)f2bf(a) | ((unsigned int)f2bf(b) << 16);
}

__device__ __forceinline__ void fma4_fp8(float* acc, unsigned int d, float w) {
    floatx2 lo = __builtin_amdgcn_cvt_pk_f32_fp8(d, false);
    floatx2 hi = __builtin_amdgcn_cvt_pk_f32_fp8(d, true);
    acc[0] = fmaf(w, lo.x, acc[0]);
    acc[1] = fmaf(w, lo.y, acc[1]);
    acc[2] = fmaf(w, hi.x, acc[2]);
    acc[3] = fmaf(w, hi.y, acc[3]);
}
__device__ __forceinline__ void fma16_fp8(float* acc, uint4 a, float w) {
    fma4_fp8(acc + 0,  a.x, w); fma4_fp8(acc + 4,  a.y, w);
    fma4_fp8(acc + 8,  a.z, w); fma4_fp8(acc + 12, a.w, w);
}

// pack 8 fp32 (two float4) -> one bfrag
__device__ __forceinline__ bfrag pack8(float4 f0, float4 f1) {
    bfrag a;
    unsigned int* au = reinterpret_cast<unsigned int*>(&a);
    au[0] = pk2(f0.x, f0.y); au[1] = pk2(f0.z, f0.w);
    au[2] = pk2(f1.x, f1.y); au[3] = pk2(f1.z, f1.w);
    return a;
}

// ---------------- fold (blocks 0..128) + hist (blocks 129+) in one dispatch ----------------
__global__ __launch_bounds__(256) void fold_hist(
    const float* __restrict__ pre_w, const float* __restrict__ pre_b,
    const float* __restrict__ g1, const float* __restrict__ be1,
    const float* __restrict__ m1, const float* __restrict__ v1,
    const float* __restrict__ upd_w, const float* __restrict__ upd_b,
    const float* __restrict__ g2, const float* __restrict__ be2,
    const float* __restrict__ m2, const float* __restrict__ v2,
    ushort_t* __restrict__ W1T, ushort_t* __restrict__ W2T,
    float* __restrict__ b1f, float* __restrict__ b2f,
    const int* __restrict__ edges, int* __restrict__ counts,
    int* __restrict__ rankb, int nEdges, int histBlocks) {
    const int t = threadIdx.x;
    if (blockIdx.x == 0) {
        __shared__ float t1[F], t2[TWO_F];
        if (t < F) {
            float s = g1[t] * rsqrtf(v1[t] + BN_EPS);
            t1[t] = be1[t] - m1[t] * s;
        }
        {
            float s = g2[t] * rsqrtf(v2[t] + BN_EPS);
            t2[t] = be2[t] - m2[t] * s;
        }
        __syncthreads();
        if (t < F) {
            float acc = pre_b[t];
            #pragma unroll 16
            for (int k = 0; k < F; ++k) acc = fmaf(t1[k], pre_w[k * F + t], acc);
            b1f[t] = acc;
        } else {
            int j = t - F;
            float acc = upd_b[j];
            #pragma unroll 16
            for (int k = 0; k < TWO_F; ++k) acc = fmaf(t2[k], upd_w[k * F + j], acc);
            b2f[j] = acc;
        }
    } else if (blockIdx.x <= 128) {
        int idx = (blockIdx.x - 1) * 256 + t;
        if (idx < F * F) {
            int k = idx & (F - 1), n = idx >> 7;
            float s = g1[k] * rsqrtf(v1[k] + BN_EPS);
            W1T[idx] = f2bf(s * pre_w[k * F + n]);
        }
        {
            int k = idx & (TWO_F - 1), n = idx >> 8;
            float s = g2[k] * rsqrtf(v2[k] + BN_EPS);
            W2T[idx] = f2bf(s * upd_w[k * F + n]);
        }
    } else {
        int b = blockIdx.x - 129;
        for (int i = b * 256 + t; i < nEdges; i += histBlocks * 256) {
            int rk = atomicAdd(&counts[edges[i]], 1);
            rankb[i] = rk;
        }
    }
}

// ---------------- CSR scans ----------------
__global__ __launch_bounds__(1024) void scan_pass1(const int* __restrict__ counts,
                                                   int* __restrict__ offsets,
                                                   int* __restrict__ blocksums, int n) {
    __shared__ int sb[1024];
    const int t = threadIdx.x;
    int idx = blockIdx.x * 1024 + t;
    int v = (idx < n) ? counts[idx] : 0;
    sb[t] = v;
    __syncthreads();
    for (int off = 1; off < 1024; off <<= 1) {
        int x = (t >= off) ? sb[t - off] : 0;
        __syncthreads();
        sb[t] += x;
        __syncthreads();
    }
    if (idx < n) offsets[idx + 1] = sb[t];
    if (t == 1023) blocksums[blockIdx.x] = sb[t];
}

__global__ __launch_bounds__(1024) void scan_pass3(const int* __restrict__ counts,
                                                   int* __restrict__ offsets,
                                                   const int* __restrict__ blocksums,
                                                   int* __restrict__ cursor, int n) {
    __shared__ int sb[1024];
    const int t = threadIdx.x;
    sb[t] = (t < blockIdx.x) ? blocksums[t] : 0;
    __syncthreads();
    #pragma unroll
    for (int off = 512; off > 0; off >>= 1) {
        if (t < off) sb[t] += sb[t + off];
        __syncthreads();
    }
    int base = sb[0];
    int idx = blockIdx.x * 1024 + t;
    if (idx < n) {
        int incl = offsets[idx + 1] + base;
        offsets[idx + 1] = incl;
        cursor[idx] = incl - counts[idx];
    }
    if (blockIdx.x == 0 && t == 0) offsets[0] = 0;
}

// ---------------- gemm1 (swapped operands, W1T in LDS fragment layout) + fill ----------------
// LDS holds W1 as linear 16B MFMA fragments [cb][kk][quad][m] -> per-instruction lane
// address = base + lane*16: conflict-free ds_read_b128, all bases imm offsets.
// D[feat][node]: lane = node(m), feats cb*16+quad*4+i -> 2x cvt_pk_fp8 -> dword G8 store.
__global__ __launch_bounds__(256) void gemm1_fill(
    const float* __restrict__ nodes, const ushort_t* __restrict__ W1T,
    const float* __restrict__ b1f, uchar_t* __restrict__ G8, int nNodes,
    const int* __restrict__ edges, const float* __restrict__ ew,
    const int* __restrict__ offsets, const int* __restrict__ rankb,
    int2* __restrict__ csr, int nEdges, int gemmBlocks, int fillBlocks, int nTiles) {
    __shared__ ushort_t Wl[16384];   // 32 KB fragment-layout W1
    __shared__ float bsm[F];
    const int t = threadIdx.x;

    if (blockIdx.x >= gemmBlocks) {   // fill part: no atomics, pure scatter
        int b = blockIdx.x - gemmBlocks;
        for (int e = b * 256 + t; e < nEdges; e += fillBlocks * 256) {
            int dst = edges[e];
            int pos = offsets[dst] + rankb[e];
            csr[pos] = make_int2(edges[nEdges + e], __float_as_int(ew[e]));
        }
        return;
    }

    // stage W1T -> LDS fragment layout: chunk c = ((cb*4+kk)*4+quad)*16+m
    for (int c = t; c < 2048; c += 256) {
        int m_ = c & 15, quad_ = (c >> 4) & 3, kk_ = (c >> 6) & 3, cb_ = c >> 8;
        int feat = cb_ * 16 + m_;
        *reinterpret_cast<uint4*>(Wl + (size_t)c * 8) =
            *reinterpret_cast<const uint4*>(W1T + (size_t)feat * F + kk_ * 32 + quad_ * 8);
    }
    if (t < F) bsm[t] = b1f[t];
    __syncthreads();

    const int lane = t & 63, w = t >> 6;
    const int m = lane & 15, quad = lane >> 4;

    for (int tile = blockIdx.x; tile < nTiles; tile += gemmBlocks) {
        const int node = tile * 64 + w * 16 + m;
        const int sn = (node < nNodes) ? node : 0;
        const float* np = nodes + (size_t)sn * F + quad * 8;

        bfrag nf[4];
        #pragma unroll
        for (int kk = 0; kk < 4; ++kk) {
            float4 f0 = *reinterpret_cast<const float4*>(np + kk * 32);
            float4 f1 = *reinterpret_cast<const float4*>(np + kk * 32 + 4);
            nf[kk] = pack8(f0, f1);
        }

        ffrag acc[8];
        #pragma unroll
        for (int cb = 0; cb < 8; ++cb) acc[cb] = (ffrag){0.f, 0.f, 0.f, 0.f};

        #pragma unroll
        for (int kk = 0; kk < 4; ++kk) {
            #pragma unroll
            for (int cb = 0; cb < 8; ++cb) {
                bfrag a = *reinterpret_cast<const bfrag*>(
                    Wl + (size_t)((((cb * 4 + kk) * 4 + quad) * 16 + m) * 8));
                acc[cb] = __builtin_amdgcn_mfma_f32_16x16x32_bf16(a, nf[kk], acc[cb], 0, 0, 0);
            }
        }

        if (node < nNodes) {
            #pragma unroll
            for (int cb = 0; cb < 8; ++cb) {
                float4 bj = *reinterpret_cast<const float4*>(bsm + cb * 16 + quad * 4);
                float v0 = gelu_exact(acc[cb][0] + bj.x);
                float v1 = gelu_exact(acc[cb][1] + bj.y);
                float v2 = gelu_exact(acc[cb][2] + bj.z);
                float v3 = gelu_exact(acc[cb][3] + bj.w);
                int pw = __builtin_amdgcn_cvt_pk_fp8_f32(v0, v1, 0, false);
                pw = __builtin_amdgcn_cvt_pk_fp8_f32(v2, v3, pw, true);
                *reinterpret_cast<unsigned int*>(
                    G8 + (size_t)node * F + cb * 16 + quad * 4) = (unsigned int)pw;
            }
        }
    }
}

// ---------------- gather_agg: pure aggregation, no LDS, no barriers ----------------
__global__ __launch_bounds__(256) void gather_agg(
    const uchar_t* __restrict__ G8, const int* __restrict__ offsets,
    const int2* __restrict__ csr, ushort_t* __restrict__ agg, int nNodes) {
    const int t = threadIdx.x;
    const int gid = blockIdx.x * 32 + (t >> 3);
    const int q = t & 7;
    if (gid >= nNodes) return;
    const int s = offsets[gid], e = offsets[gid + 1];

    float acc[16];
    #pragma unroll
    for (int j = 0; j < 16; ++j) acc[j] = 0.f;

    int i = s;
    while (i < e) {
        int c = e - i;
        c = (c > 8) ? 8 : c;
        uint4 av[8];
        float wv[8];
        #pragma unroll
        for (int j = 0; j < 8; ++j) {
            if (j < c) {
                int2 m = csr[i + j];
                wv[j] = __int_as_float(m.y);
                av[j] = *reinterpret_cast<const uint4*>(
                    G8 + (size_t)(unsigned int)m.x * F + q * 16);
            }
        }
        #pragma unroll
        for (int j = 0; j < 8; ++j)
            if (j < c) fma16_fp8(acc, av[j], wv[j]);
        i += c;
    }

    const int deg = e - s;
    const float inv = (deg > 0) ? 1.0f / ((float)deg * (float)F) : 0.f;  // counter = deg*F quirk
    uint4 pv0, pv1;
    pv0.x = pk2(acc[0] * inv, acc[1] * inv);  pv0.y = pk2(acc[2] * inv, acc[3] * inv);
    pv0.z = pk2(acc[4] * inv, acc[5] * inv);  pv0.w = pk2(acc[6] * inv, acc[7] * inv);
    pv1.x = pk2(acc[8] * inv, acc[9] * inv);  pv1.y = pk2(acc[10] * inv, acc[11] * inv);
    pv1.z = pk2(acc[12] * inv, acc[13] * inv); pv1.w = pk2(acc[14] * inv, acc[15] * inv);
    uint4* d = reinterpret_cast<uint4*>(agg + (size_t)gid * F + q * 16);
    d[0] = pv0; d[1] = pv1;
}

// ---------------- gemm2 (swapped operands, W2T in LDS fragment layout, 512 thr) ----------------
// Fragment layout [cb][kk][quad][m] (64 KB), conflict-free ds_read_b128.
// B = [nodes fp32 packed | agg bf16] per-lane node rows; 8 waves x 16 nodes = 128/block.
__global__ __launch_bounds__(512) void gemm2(
    const float* __restrict__ nodes, const ushort_t* __restrict__ agg,
    const ushort_t* __restrict__ W2T, const float* __restrict__ b2f,
    float* __restrict__ out, int nNodes) {
    __shared__ ushort_t Wl[32768];   // 64 KB fragment-layout W2
    __shared__ float bsm[F];
    const int t = threadIdx.x;

    // stage: chunk c = ((cb*8+kk)*4+quad)*16+m
    for (int c = t; c < 4096; c += 512) {
        int m_ = c & 15, quad_ = (c >> 4) & 3, kk_ = (c >> 6) & 7, cb_ = c >> 9;
        int feat = cb_ * 16 + m_;
        *reinterpret_cast<uint4*>(Wl + (size_t)c * 8) =
            *reinterpret_cast<const uint4*>(W2T + (size_t)feat * TWO_F + kk_ * 32 + quad_ * 8);
    }
    if (t < F) bsm[t] = b2f[t];
    __syncthreads();

    const int lane = t & 63, w = t >> 6;
    const int m = lane & 15, quad = lane >> 4;

    const int node = blockIdx.x * 128 + w * 16 + m;
    const int sn = (node < nNodes) ? node : 0;
    const float*    np = nodes + (size_t)sn * F + quad * 8;
    const ushort_t* pa = agg   + (size_t)sn * F + quad * 8;

    bfrag nf[8];
    #pragma unroll
    for (int kk = 0; kk < 4; ++kk) {
        float4 f0 = *reinterpret_cast<const float4*>(np + kk * 32);
        float4 f1 = *reinterpret_cast<const float4*>(np + kk * 32 + 4);
        nf[kk] = pack8(f0, f1);
    }
    #pragma unroll
    for (int kk = 4; kk < 8; ++kk)
        nf[kk] = *reinterpret_cast<const bfrag*>(pa + (kk - 4) * 32);

    ffrag acc[8];
    #pragma unroll
    for (int cb = 0; cb < 8; ++cb) acc[cb] = (ffrag){0.f, 0.f, 0.f, 0.f};

    #pragma unroll
    for (int kk = 0; kk < 8; ++kk) {
        #pragma unroll
        for (int cb = 0; cb < 8; ++cb) {
            bfrag a = *reinterpret_cast<const bfrag*>(
                Wl + (size_t)((((cb * 8 + kk) * 4 + quad) * 16 + m) * 8));
            acc[cb] = __builtin_amdgcn_mfma_f32_16x16x32_bf16(a, nf[kk], acc[cb], 0, 0, 0);
        }
    }

    if (node < nNodes) {
        #pragma unroll
        for (int cb = 0; cb < 8; ++cb) {
            float4 bj = *reinterpret_cast<const float4*>(bsm + cb * 16 + quad * 4);
            float4 o;
            o.x = gelu_exact(acc[cb][0] + bj.x);
            o.y = gelu_exact(acc[cb][1] + bj.y);
            o.z = gelu_exact(acc[cb][2] + bj.z);
            o.w = gelu_exact(acc[cb][3] + bj.w);
            *reinterpret_cast<float4*>(out + (size_t)node * F + cb * 16 + quad * 4) = o;
        }
    }
}

extern "C" void kernel_launch(void* const* d_in, const int* in_sizes, int n_in,
                              void* d_out, int out_size, void* d_ws, size_t ws_size,
                              hipStream_t stream) {
    const float* nodes  = (const float*)d_in[0];
    const int*   edges  = (const int*)d_in[1];
    const float* ew     = (const float*)d_in[2];
    const float* pre_g  = (const float*)d_in[3];
    const float* pre_be = (const float*)d_in[4];
    const float* pre_m  = (const float*)d_in[5];
    const float* pre_v  = (const float*)d_in[6];
    const float* pre_w  = (const float*)d_in[7];
    const float* pre_b  = (const float*)d_in[8];
    const float* upd_g  = (const float*)d_in[9];
    const float* upd_be = (const float*)d_in[10];
    const float* upd_m  = (const float*)d_in[11];
    const float* upd_v  = (const float*)d_in[12];
    const float* upd_w  = (const float*)d_in[13];
    const float* upd_b  = (const float*)d_in[14];
    float* out = (float*)d_out;

    const int nNodes = in_sizes[0] / F;
    const int nEdges = in_sizes[2];
    const int nChunks = (nNodes + 1023) / 1024;
    const int histBlocks = 1024;
    const int fillBlocks = 512;
    const int nTiles = (nNodes + 63) / 64;
    const int gemmBlocks = (nTiles < 1024) ? nTiles : 1024;   // 4 blocks/CU persistent

    // ws layout (16B aligned blocks)
    char* p = (char*)d_ws;
    int*      counts    = (int*)p;       p += (size_t)nNodes * 4;
    int*      offsets   = (int*)p;       p += (size_t)(nNodes + 4) * 4;
    int*      cursor    = (int*)p;       p += (size_t)nNodes * 4;
    int*      blocksums = (int*)p;       p += 1024 * 4;
    int2*     csr       = (int2*)p;      p += (size_t)nEdges * 8;
    float*    b1f       = (float*)p;     p += F * 4;
    float*    b2f       = (float*)p;     p += F * 4;
    ushort_t* W1T       = (ushort_t*)p;  p += F * F * 2;
    ushort_t* W2T       = (ushort_t*)p;  p += TWO_F * F * 2;
    uchar_t*  G8        = (uchar_t*)p;   p += (size_t)nNodes * F;
    ushort_t* agg       = (ushort_t*)p;  p += (size_t)nNodes * F * 2;
    int*      rankb     = (int*)p;       // nEdges * 4

    hipMemsetAsync(counts, 0, (size_t)nNodes * 4, stream);

    fold_hist<<<129 + histBlocks, 256, 0, stream>>>(
        pre_w, pre_b, pre_g, pre_be, pre_m, pre_v,
        upd_w, upd_b, upd_g, upd_be, upd_m, upd_v,
        W1T, W2T, b1f, b2f, edges, counts, rankb, nEdges, histBlocks);

    scan_pass1<<<nChunks, 1024, 0, stream>>>(counts, offsets, blocksums, nNodes);
    scan_pass3<<<nChunks, 1024, 0, stream>>>(counts, offsets, blocksums, cursor, nNodes);

    gemm1_fill<<<gemmBlocks + fillBlocks, 256, 0, stream>>>(
        nodes, W1T, b1f, G8, nNodes, edges, ew, offsets, rankb, csr, nEdges,
        gemmBlocks, fillBlocks, nTiles);

    gather_agg<<<(nNodes + 31) / 32, 256, 0, stream>>>(
        G8, offsets, csr, agg, nNodes);

    gemm2<<<(nNodes + 127) / 128, 512, 0, stream>>>(
        nodes, agg, W2T, b2f, out, nNodes);
}